// Round 1
// baseline (13398.784 us; speedup 1.0000x reference)
//
#include <hip/hip_runtime.h>

#define HID 64
#define NF 8

typedef float f2 __attribute__((ext_vector_type(2)));
typedef float f4 __attribute__((ext_vector_type(4)));

union CV { long long ll; int c[2]; };

template <int CTRL>
__device__ __forceinline__ float qp(float x) {
  return __int_as_float(
      __builtin_amdgcn_update_dpp(0, __float_as_int(x), CTRL, 0xF, 0xF, true));
}

// 512 threads = 8 waves, 2/SIMD. Waves 0-3: layer-0 group. Waves 4-7: layer-1
// (one step behind). R8 changes vs R7 (cell math bit-identical):
//  * combined wait: single ds_read_b64 of both phase counters per poll
//    (was two sequential acquire round-trips).
//  * early release: counter add immediately after the cell's LDS h-write;
//    all head work (x-proj, hid, out, IO) runs post-release and overlaps
//    siblings' next-phase cells.
//  * head rebalance: hid split waves 2&3 (16 rows each); wave1 = out+store;
//    wave0 = tbuf refill with split issue(==12)/ds_write(==28) so the
//    vmcnt drain never stalls a phase.
//  * out lag 4->5 (wave1 reads hidS[(t-2)&3]) so the hidS producer->consumer
//    edge is covered by release(t-1) ⊇ all phase t-2 work. Store window
//    moves to (t&31)==5, t>=37; epilogue covers the last 64 rows.
__global__ __launch_bounds__(512, 2) void decoder_p8(
    const float* __restrict__ h0in, const float* __restrict__ c0in,
    const float* __restrict__ diffp, const float* __restrict__ target,
    const float* __restrict__ Wih0, const float* __restrict__ Whh0,
    const float* __restrict__ bih0, const float* __restrict__ bhh0,
    const float* __restrict__ Wih1, const float* __restrict__ Whh1,
    const float* __restrict__ bih1, const float* __restrict__ bhh1,
    const float* __restrict__ Whid, const float* __restrict__ bhidp,
    const float* __restrict__ Woutp, const float* __restrict__ boutp,
    float* __restrict__ outp, const int T)
{
  const int tid = threadIdx.x;
  const int wv  = tid >> 6;
  const int l   = tid & 63;
  const int q   = l >> 2;
  const int k   = l & 3;
  const bool isL1 = (wv >= 4);
  const int u   = 16 * (wv & 3) + q;   // hidden unit (this quad's)
  const int r   = 64 * k + u;          // final gate row for this lane
  const bool isk0 = (k == 0);
  const bool isg  = (k == 2);
  const float am = isg ? 2.0f : 1.0f;  // act: y=am*x, a=am*sigma(y)+ab
  const float ab = isg ? -1.0f : 0.0f;

  __shared__ alignas(256) float h0r[4][64];
  __shared__ alignas(256) float h1r[4][64];
  __shared__ alignas(256) float hidS[4][32];
  __shared__ alignas(256) float obuf[64 * NF];
  __shared__ alignas(256) float tbuf[2][32 * NF];
  __shared__ alignas(8) int cnt[2];

  f2 wreg[64];
  float b_ = 0.f, xd = 0.f;
  float bh = 0.f, bo_ = 0.f;
  f4 tr0 = {0.f, 0.f, 0.f, 0.f}, tr1 = {0.f, 0.f, 0.f, 0.f};

  if (isL1) {
    const float* Wsrc = (k < 2) ? Wih1 : Whh1;
    const int co = 32 * (k & 1);
    #pragma unroll
    for (int j = 0; j < 4; ++j) {
      const int row = 64 * ((k + j) & 3) + u;
      const float* rp = Wsrc + row * HID + co;
      #pragma unroll
      for (int c = 0; c < 8; ++c) {
        f4 v = *(const f4*)(rp + 4 * ((c + 2 * k) & 7));
        wreg[16 * j + 2 * c]     = v.lo;
        wreg[16 * j + 2 * c + 1] = v.hi;
      }
    }
    b_ = bih1[r] + bhh1[r];
  } else {
    #pragma unroll
    for (int j = 0; j < 4; ++j) {
      const int row = 64 * ((k + j) & 3) + u;
      const float* rp = Whh0 + row * HID + 16 * k;
      #pragma unroll
      for (int c = 0; c < 4; ++c) {
        f4 v = *(const f4*)(rp + 4 * ((c + k) & 3));
        wreg[8 * j + 2 * c]     = v.lo;
        wreg[8 * j + 2 * c + 1] = v.hi;
      }
    }
    b_ = bih0[r] + bhh0[r];
    {
      const float* ra = Wih0 + r * 14;
      #pragma unroll
      for (int c = 0; c < 4; ++c) wreg[48 + c] = (f2){ra[2 * c], ra[2 * c + 1]};
      #pragma unroll
      for (int m = 0; m < 6; ++m) xd += ra[8 + m] * diffp[m];
    }
    if (wv >= 2) {
      // hid head: waves 2,3 take 16 rows each of Whid (32x64)
      const int R = 16 * (wv - 2) + q;
      const float* rp = Whid + R * HID + 16 * k;
      #pragma unroll
      for (int c = 0; c < 4; ++c) {
        f4 v = *(const f4*)(rp + 4 * ((c + k) & 3));
        wreg[32 + 2 * c]     = v.lo;
        wreg[32 + 2 * c + 1] = v.hi;
      }
      bh = bhidp[R];
    } else if (wv == 1 && q < 8) {
      const float* rp = Woutp + q * 32 + 8 * k;
      #pragma unroll
      for (int c = 0; c < 2; ++c) {
        f4 v = *(const f4*)(rp + 4 * ((c + k) & 1));
        wreg[32 + 2 * c]     = v.lo;
        wreg[32 + 2 * c + 1] = v.hi;
      }
      bo_ = boutp[q];
    }
  }

  float cS = 0.f, hS = 0.f;
  if (isk0) cS = isL1 ? c0in[64 + u] : c0in[u];
  // seeds in slot 3 (= states at t-1 for t=0 reads)
  if (wv == 0) h0r[3][l] = h0in[l];
  else if (wv == 1) h1r[3][l] = h0in[64 + l];
  else if (wv == 2) {
    *(f4*)&((float*)tbuf)[l * 8]     = *(const f4*)&target[l * 8];
    *(f4*)&((float*)tbuf)[l * 8 + 4] = *(const f4*)&target[l * 8 + 4];
  }
  if (tid == 0) { cnt[0] = 0; cnt[1] = 0; }
  float xc = 0.f;   // x(0) = zeros
  __syncthreads();

  int tgt  = 0;                        // 4t
  int tgtm = isL1 ? 0 : -4;            // 4(t-1) for L0, 4t for L1
  const int tend = T + 4;
  for (int t = 0; t <= tend; ++t) {
    // ---- combined wait: one ds_read_b64 per poll ----
    {
      CV v;
      do {
        v.ll = __hip_atomic_load((const long long*)cnt, __ATOMIC_ACQUIRE,
                                 __HIP_MEMORY_SCOPE_WORKGROUP);
      } while (v.c[0] < tgt || v.c[1] < tgtm);
    }
    const int sR0 = (t - 1) & 3;   // h0[t-1]
    if (isL1) {
      // ---------- layer 1: h1[t-1] = cell(h0[t-1], h1[t-2]) ----------
      if (t >= 1 && t <= T) {
        const int sR1 = (t - 2) & 3;
        const float* base = (k < 2) ? &h0r[sR0][32 * (k & 1)]
                                    : &h1r[sR1][32 * (k & 1)];
        f2 P0 = {0.f,0.f}, P1 = {0.f,0.f}, P2 = {0.f,0.f}, P3 = {0.f,0.f};
        #pragma unroll
        for (int c = 0; c < 8; ++c) {
          f4 v = *(const f4*)(base + 4 * ((c + 2 * k) & 7));
          P0 += wreg[2*c] * v.lo;      P0 += wreg[2*c+1] * v.hi;
          P1 += wreg[16+2*c] * v.lo;   P1 += wreg[16+2*c+1] * v.hi;
          P2 += wreg[32+2*c] * v.lo;   P2 += wreg[32+2*c+1] * v.hi;
          P3 += wreg[48+2*c] * v.lo;   P3 += wreg[48+2*c+1] * v.hi;
        }
        float p0 = P0.x + P0.y, p1 = P1.x + P1.y;
        float p2 = P2.x + P2.y, p3 = P3.x + P3.y;
        float g = ((p0 + qp<0x39>(p3)) + (qp<0x4E>(p2) + qp<0x93>(p1))) + b_;
        float e = __expf(-g * am);
        float s = __fdividef(1.0f, 1.0f + e);
        float a = fmaf(s, am, ab);
        float A1 = qp<0xB1>(a), A2 = qp<0x4E>(a), A3 = qp<0x1B>(a);
        if (isk0) {
          cS = A1 * cS + a * A2;
          float e2 = __expf(-2.0f * cS);
          hS = A3 * (__fdividef(2.0f, 1.0f + e2) - 1.0f);
          h1r[(t - 1) & 3][u] = hS;
        }
      }
      // ---- early release (nothing follows for L1) ----
      if (l == 0)
        __hip_atomic_fetch_add(&cnt[1], 1, __ATOMIC_RELEASE,
                               __HIP_MEMORY_SCOPE_WORKGROUP);
    } else {
      // ---------- layer 0: h0[t] = cell(x(t), h0[t-1]) ----------
      if (t < T) {
        const float* base = &h0r[sR0][16 * k];
        f2 P0 = {0.f,0.f}, P1 = {0.f,0.f}, P2 = {0.f,0.f}, P3 = {0.f,0.f};
        #pragma unroll
        for (int c = 0; c < 4; ++c) {
          f4 v = *(const f4*)(base + 4 * ((c + k) & 3));
          P0 += wreg[2*c] * v.lo;      P0 += wreg[2*c+1] * v.hi;
          P1 += wreg[8+2*c] * v.lo;    P1 += wreg[8+2*c+1] * v.hi;
          P2 += wreg[16+2*c] * v.lo;   P2 += wreg[16+2*c+1] * v.hi;
          P3 += wreg[24+2*c] * v.lo;   P3 += wreg[24+2*c+1] * v.hi;
        }
        float p0 = P0.x + P0.y, p1 = P1.x + P1.y;
        float p2 = P2.x + P2.y, p3 = P3.x + P3.y;
        float g = ((p0 + qp<0x39>(p3)) + (qp<0x4E>(p2) + qp<0x93>(p1))) + b_ + xc;
        float e = __expf(-g * am);
        float s = __fdividef(1.0f, 1.0f + e);
        float a = fmaf(s, am, ab);
        float A1 = qp<0xB1>(a), A2 = qp<0x4E>(a), A3 = qp<0x1B>(a);
        if (isk0) {
          cS = A1 * cS + a * A2;
          float e2 = __expf(-2.0f * cS);
          hS = A3 * (__fdividef(2.0f, 1.0f + e2) - 1.0f);
          h0r[t & 3][u] = hS;
        }
      }
      // ---- early release: recurrence edge published before head work ----
      if (l == 0)
        __hip_atomic_fetch_add(&cnt[0], 1, __ATOMIC_RELEASE,
                               __HIP_MEMORY_SCOPE_WORKGROUP);
      // ---------- x-proj for phase t+1 (uses target[t]) ----------
      if (t < T - 1) {
        const f4* trow = (const f4*)&tbuf[(t >> 5) & 1][(t & 31) * NF];
        f4 r0 = trow[0], r1 = trow[1];
        f2 s = wreg[48] * r0.lo; s += wreg[49] * r0.hi;
        s += wreg[50] * r1.lo;   s += wreg[51] * r1.hi;
        xc = xd + s.x + s.y;
      } else xc = 0.f;
      // ---------- waves 2,3: hid(t-3) halves from h1[t-3] ----------
      if (wv >= 2 && t >= 3 && t <= T + 2) {
        const float* hp = &h1r[(t - 3) & 3][16 * k];
        f2 pa = {0.f,0.f};
        #pragma unroll
        for (int c = 0; c < 4; ++c) {
          f4 v = *(const f4*)(hp + 4 * ((c + k) & 3));
          pa += wreg[32+2*c] * v.lo; pa += wreg[32+2*c+1] * v.hi;
        }
        float sa = pa.x + pa.y; sa += qp<0xB1>(sa); sa += qp<0x4E>(sa);
        if (isk0) hidS[t & 3][16 * (wv - 2) + q] = sa + bh;
      }
      // ---------- wave1: out(t-5) + out-store ----------
      if (wv == 1) {
        if (q < 8 && t >= 5) {
          const float* hp = &hidS[(t - 2) & 3][8 * k];
          f2 po = {0.f,0.f};
          #pragma unroll
          for (int c = 0; c < 2; ++c) {
            f4 v = *(const f4*)(hp + 4 * ((c + k) & 1));
            po += wreg[32+2*c] * v.lo; po += wreg[32+2*c+1] * v.hi;
          }
          float so = po.x + po.y; so += qp<0xB1>(so); so += qp<0x4E>(so);
          if (isk0) obuf[((t - 5) & 63) * NF + q] = rintf(so + bo_);
        }
        if (l >= 32 && (t & 31) == 5 && t >= 37) {
          const int j = l - 32;
          #pragma unroll
          for (int ii = 0; ii < 2; ++ii) {
            const int fidx = 2 * j + ii;
            const int s = (t - 37) + (fidx >> 1);
            const int c4 = (fidx & 1) * 4;
            *(f4*)&outp[s * NF + c4] = *(const f4*)&obuf[(s & 63) * NF + c4];
          }
        }
      }
      // ---------- wave0: tbuf refill, split issue(==12)/write(==28) ----------
      if (wv == 0 && l >= 32) {
        const int j = l - 32;
        const int ph = t & 31;
        if (ph == 12) {
          const int cl = (t >> 5) + 1;
          if (cl * 32 < T) {
            tr0 = *(const f4*)&target[cl * 256 + j * 8];
            tr1 = *(const f4*)&target[cl * 256 + j * 8 + 4];
          }
        } else if (ph == 28) {
          const int cl = (t >> 5) + 1;
          if (cl * 32 < T) {
            *(f4*)&tbuf[cl & 1][j * 8]     = tr0;
            *(f4*)&tbuf[cl & 1][j * 8 + 4] = tr1;
          }
        }
      }
    }
    tgt += 4; tgtm += 4;
  }
  __syncthreads();

  // ================= EPILOGUE =================
  {
    int s0 = (((T - 1) >> 5) << 5) - 32;   // last <=64 rows (still in obuf ring)
    if (s0 < 0) s0 = 0;
    for (int idx = tid; idx < (T - s0) * NF; idx += 512) {
      const int s = s0 + (idx >> 3);
      outp[s * NF + (idx & 7)] = obuf[(s & 63) * NF + (idx & 7)];
    }
  }
  if (isk0) {
    const int base = T * NF;
    if (!isL1) {
      outp[base + u]        = hS;   // h_final layer 0
      outp[base + 128 + u]  = cS;   // c_final layer 0
    } else {
      outp[base + 64 + u]   = hS;   // h_final layer 1
      outp[base + 192 + u]  = cS;   // c_final layer 1
    }
  }
}

extern "C" void kernel_launch(void* const* d_in, const int* in_sizes, int n_in,
                              void* d_out, int out_size, void* d_ws, size_t ws_size,
                              hipStream_t stream) {
  const float* h0in   = (const float*)d_in[1];
  const float* c0in   = (const float*)d_in[2];
  const float* diffp  = (const float*)d_in[3];
  const float* target = (const float*)d_in[4];
  const float* Wih0   = (const float*)d_in[5];
  const float* Whh0   = (const float*)d_in[6];
  const float* bih0   = (const float*)d_in[7];
  const float* bhh0   = (const float*)d_in[8];
  const float* Wih1   = (const float*)d_in[9];
  const float* Whh1   = (const float*)d_in[10];
  const float* bih1   = (const float*)d_in[11];
  const float* bhh1   = (const float*)d_in[12];
  const float* Whid   = (const float*)d_in[13];
  const float* bhidp  = (const float*)d_in[14];
  const float* Woutp  = (const float*)d_in[15];
  const float* boutp  = (const float*)d_in[16];
  float* outp = (float*)d_out;
  const int T = in_sizes[4] / NF;

  decoder_p8<<<dim3(1), dim3(512), 0, stream>>>(
      h0in, c0in, diffp, target,
      Wih0, Whh0, bih0, bhh0,
      Wih1, Whh1, bih1, bhh1,
      Whid, bhidp, Woutp, boutp,
      outp, T);
}